// Round 14
// baseline (211.669 us; speedup 1.0000x reference)
//
#include <hip/hip_runtime.h>
#include <math.h>
#include <stdint.h>

#define B_ 4
#define C_ 256
#define HW_ 4096
#define G_ 8
#define H_ 4
#define DH_ 64
#define GRP_ELEMS (32 * HW_)             // 131072
#define NCHUNK 16
#define CHUNK_ELEMS (GRP_ELEMS / NCHUNK) // 8192
#define EPS 1e-5f
#define NT_ (HW_ / 64)                   // 64 j-tiles
#define QSCALE 0.04508422f               // (1/32) * log2(e)

typedef __attribute__((ext_vector_type(8))) short short8;
typedef __attribute__((ext_vector_type(4))) float f32x4;
typedef __attribute__((ext_vector_type(4))) unsigned int u32x4;
typedef const __attribute__((address_space(1))) uint32_t* gas1_t;
typedef __attribute__((address_space(3))) uint32_t* las3_t;

__device__ __forceinline__ ushort f2bf(float x) {
    unsigned u = __builtin_bit_cast(unsigned, x);
    u += 0x7FFFu + ((u >> 16) & 1u);
    return (ushort)(u >> 16);
}
__device__ __forceinline__ uint32_t cvt_pk_bf16(float lo, float hi) {
    uint32_t r;
    asm("v_cvt_pk_bf16_f32 %0, %1, %2" : "=v"(r) : "v"(lo), "v"(hi));
    return r;
}

// ---------------- GN stage-1 partial sums + weight convert (merged) --------
__global__ __launch_bounds__(256) void gn_part_wcvt(const float* __restrict__ x,
                                                    float* __restrict__ part,
                                                    const float* __restrict__ wq,
                                                    const float* __restrict__ wp,
                                                    ushort* __restrict__ wqb,
                                                    ushort* __restrict__ wpb) {
    int t = threadIdx.x;
    if (blockIdx.x >= 512) {          // weight convert: 1024 blocks
        int i = (blockIdx.x - 512) * 256 + t;
        if (i < 768 * 256) {
            float s = (i < 256 * 256) ? QSCALE : 1.0f;
            wqb[i] = f2bf(wq[i] * s);
        } else {
            wpb[i - 768 * 256] = f2bf(wp[i - 768 * 256]);
        }
        return;
    }
    int bg = blockIdx.x >> 4;
    int chunk = blockIdx.x & 15;
    const float4* p = (const float4*)(x + (size_t)bg * GRP_ELEMS + (size_t)chunk * CHUNK_ELEMS);
    float s = 0.f, ss = 0.f;
#pragma unroll
    for (int i = 0; i < 8; ++i) {
        float4 v = p[t + i * 256];
        s  += v.x + v.y + v.z + v.w;
        ss += v.x * v.x + v.y * v.y + v.z * v.z + v.w * v.w;
    }
#pragma unroll
    for (int off = 32; off; off >>= 1) {
        s  += __shfl_xor(s, off, 64);
        ss += __shfl_xor(ss, off, 64);
    }
    __shared__ float ls[8];
    int wave = t >> 6, lane = t & 63;
    if (lane == 0) { ls[wave * 2] = s; ls[wave * 2 + 1] = ss; }
    __syncthreads();
    if (t == 0) {
        float S = 0.f, SS = 0.f;
#pragma unroll
        for (int w = 0; w < 4; ++w) { S += ls[w * 2]; SS += ls[w * 2 + 1]; }
        part[(bg * 16 + chunk) * 2]     = S;
        part[(bg * 16 + chunk) * 2 + 1] = SS;
    }
}

// ---------------- fused GroupNorm + QKV GEMM (round-13, unchanged) ---------
#define TSTR 264
__global__ __launch_bounds__(256) void gn_qkv(const float* __restrict__ x,
                                              const float* __restrict__ gamma,
                                              const float* __restrict__ beta,
                                              const float* __restrict__ part,
                                              const ushort* __restrict__ wqb,
                                              ushort* __restrict__ qt,
                                              ushort* __restrict__ kt,
                                              ushort* __restrict__ vv) {
    __shared__ float2 affs[256];
    __shared__ __align__(16) ushort Ts[64 * TSTR];
    int n0 = blockIdx.x * 64;
    int b  = blockIdx.y;
    int t = threadIdx.x;

    {
        int c = t;
        int bg = b * G_ + (c >> 5);
        float S = 0.f, SS = 0.f;
#pragma unroll
        for (int i = 0; i < 16; ++i) {
            S  += part[(bg * 16 + i) * 2];
            SS += part[(bg * 16 + i) * 2 + 1];
        }
        float mean = S * (1.f / GRP_ELEMS);
        float var  = SS * (1.f / GRP_ELEMS) - mean * mean;
        float inv  = rsqrtf(var + EPS);
        float a = inv * gamma[c];
        affs[c] = make_float2(a, beta[c] - mean * a);
    }
    __syncthreads();

    {
        int n4 = t & 15, cr = t >> 4;
#pragma unroll
        for (int ct = 0; ct < 16; ++ct) {
            int c = cr + 16 * ct;
            float2 p = affs[c];
            float4 v = *(const float4*)(x + ((size_t)(b * C_ + c)) * HW_ + n0 + n4 * 4);
            ushort e[4];
            e[0] = f2bf(v.x * p.x + p.y); e[1] = f2bf(v.y * p.x + p.y);
            e[2] = f2bf(v.z * p.x + p.y); e[3] = f2bf(v.w * p.x + p.y);
#pragma unroll
            for (int k = 0; k < 4; ++k) {
                int n = n4 * 4 + k;
                Ts[n * TSTR + (((c >> 3) ^ ((n >> 2) & 7)) << 3) + (c & 7)] = e[k];
            }
        }
    }
    __syncthreads();

    int w = t >> 6, lane = t & 63, l16 = lane & 15, lg = lane >> 4;

    for (int z = 0; z < 3; ++z) {
        const ushort* wz = wqb + (size_t)(z * 256 + 32 * w + l16) * C_;
        f32x4 acc[2][2][4];
#pragma unroll
        for (int j = 0; j < 2; ++j)
#pragma unroll
            for (int os = 0; os < 2; ++os)
#pragma unroll
                for (int u = 0; u < 4; ++u)
#pragma unroll
                    for (int r = 0; r < 4; ++r) acc[j][os][u][r] = 0.f;

#pragma unroll 2
        for (int ks = 0; ks < 8; ++ks) {
            short8 a00 = *(const short8*)(wz + 32 * ks + 8 * lg);
            short8 a01 = *(const short8*)(wz + 16 * C_ + 32 * ks + 8 * lg);
            short8 a10 = *(const short8*)(wz + 128 * C_ + 32 * ks + 8 * lg);
            short8 a11 = *(const short8*)(wz + 144 * C_ + 32 * ks + 8 * lg);
#pragma unroll
            for (int u = 0; u < 4; ++u) {
                int n = 16 * u + l16;
                short8 bf = *(const short8*)&Ts[n * TSTR +
                               (((4 * ks + lg) ^ ((n >> 2) & 7)) << 3)];
                acc[0][0][u] = __builtin_amdgcn_mfma_f32_16x16x32_bf16(a00, bf, acc[0][0][u], 0, 0, 0);
                acc[0][1][u] = __builtin_amdgcn_mfma_f32_16x16x32_bf16(a01, bf, acc[0][1][u], 0, 0, 0);
                acc[1][0][u] = __builtin_amdgcn_mfma_f32_16x16x32_bf16(a10, bf, acc[1][0][u], 0, 0, 0);
                acc[1][1][u] = __builtin_amdgcn_mfma_f32_16x16x32_bf16(a11, bf, acc[1][1][u], 0, 0, 0);
            }
        }

#pragma unroll
        for (int j = 0; j < 2; ++j)
#pragma unroll
            for (int os = 0; os < 2; ++os) {
                int o_base = z * 256 + 128 * j + 32 * w + 16 * os;
                if (z < 2) {
                    int h = (o_base >> 6) & 3;
                    int od0 = (o_base & 63) + 4 * lg;
                    ushort* dstb = (z ? kt : qt) + ((size_t)((b << 2) | h) * HW_) * DH_;
#pragma unroll
                    for (int u = 0; u < 4; ++u) {
                        int n = n0 + 16 * u + l16;
                        uint2 pk;
                        pk.x = cvt_pk_bf16(acc[j][os][u][0], acc[j][os][u][1]);
                        pk.y = cvt_pk_bf16(acc[j][os][u][2], acc[j][os][u][3]);
                        *(uint2*)(dstb + (size_t)n * DH_ + od0) = pk;
                    }
                } else {
                    int row0 = o_base - 512 + 4 * lg;
#pragma unroll
                    for (int u = 0; u < 4; ++u) {
                        int n = n0 + 16 * u + l16;
#pragma unroll
                        for (int r = 0; r < 4; ++r)
                            vv[((size_t)(b * C_ + row0 + r)) * HW_ + n] = f2bf(acc[j][os][u][r]);
                    }
                }
            }
    }
}

// ---------------- MFMA flash attention v10: K via LDS, V direct-global -----
// grid 512 (XCD-swizzled), 4 waves x 32 rows (2 strips). K staged (g(L) perm,
// 4 bufs, prefetch-3); V frags per-wave global (L1-resident), ping-pong
// register sets, issued one tile ahead. DS pipe halved; L1 carries V.
__global__ __launch_bounds__(256) void flash_attn_mfma(const ushort* __restrict__ qt,
                                                       const ushort* __restrict__ kt,
                                                       const ushort* __restrict__ vv,
                                                       ushort* __restrict__ attT) {
    __shared__ __align__(16) ushort Kb[4][64 * 64];   // [perm row][dh], chunks swz

    int bid = blockIdx.x;
    int wg = (bid & 7) * 64 + (bid >> 3);   // bijective: 512 = 8 * 64
    int bh = wg >> 5;
    int i0 = (wg & 31) * 128;
    int b = bh >> 2, h = bh & 3;
    int t = threadIdx.x;
    int w = t >> 6, lane = t & 63, l16 = lane & 15, lg = lane >> 4;
    const ushort* qtb = qt + (size_t)bh * HW_ * DH_;
    const ushort* ktb = kt + (size_t)bh * HW_ * DH_;
    const ushort* vb  = vv + ((size_t)(b * C_) + h * DH_) * HW_;

    short8 qf[2][2];
#pragma unroll
    for (int s = 0; s < 2; ++s)
#pragma unroll
        for (int ks = 0; ks < 2; ++ks)
            qf[s][ks] = *(const short8*)(qtb + (size_t)(i0 + 32 * w + 16 * s + l16) * DH_ + 32 * ks + 8 * lg);

    f32x4 O0[4], O1[4], lacc0, lacc1;
#pragma unroll
    for (int dt = 0; dt < 4; ++dt)
#pragma unroll
        for (int r = 0; r < 4; ++r) { O0[dt][r] = 0.f; O1[dt][r] = 0.f; }
#pragma unroll
    for (int r = 0; r < 4; ++r) { lacc0[r] = 0.f; lacc1[r] = 0.f; }
    const f32x4 Z4 = {0.f, 0.f, 0.f, 0.f};

    u32x4 ov; ov[0] = ov[1] = ov[2] = ov[3] = 0x3F803F80u;
    short8 onesf = __builtin_bit_cast(short8, ov);

    int r8 = lane >> 3, ch8 = lane & 7;
    size_t koff[2];
#pragma unroll
    for (int half = 0; half < 2; ++half) {
        int L = 16 * w + half * 8 + r8;
        int gk = (L & 0x23) | ((L & 0x0C) << 1) | ((L & 0x10) >> 2);
        koff[half] = (size_t)gk * DH_ + ((ch8 ^ (L & 7)) << 3);
    }

    auto stageK = [&](int bi, int j0) {
#pragma unroll
        for (int half = 0; half < 2; ++half) {
            int rowb = 16 * w + half * 8;
            __builtin_amdgcn_global_load_lds((gas1_t)(ktb + (size_t)j0 * DH_ + koff[half]),
                (las3_t)&Kb[bi][rowb * 64], 16, 0, 0);
        }
    };
    // V frags direct from global (L1-resident)
    auto loadV = [&](short8 (*V)[2], int j0) {
#pragma unroll
        for (int dt = 0; dt < 4; ++dt)
#pragma unroll
            for (int ks = 0; ks < 2; ++ks)
                V[dt][ks] = *(const short8*)(vb + (size_t)(16 * dt + l16) * HW_ + j0 + 32 * ks + 8 * lg);
    };

    auto qk2 = [&](int bi, f32x4* S0, f32x4* S1) {
        __builtin_amdgcn_s_setprio(1);
#pragma unroll
        for (int jt = 0; jt < 4; ++jt) {
            short8 kf0 = *(const short8*)&Kb[bi][(16 * jt + l16) * 64 +
                                                ((lg ^ (l16 & 7)) << 3)];
            S0[jt] = __builtin_amdgcn_mfma_f32_16x16x32_bf16(kf0, qf[0][0], Z4, 0, 0, 0);
            S1[jt] = __builtin_amdgcn_mfma_f32_16x16x32_bf16(kf0, qf[1][0], Z4, 0, 0, 0);
            short8 kf1 = *(const short8*)&Kb[bi][(16 * jt + l16) * 64 +
                                                (((4 + lg) ^ (l16 & 7)) << 3)];
            S0[jt] = __builtin_amdgcn_mfma_f32_16x16x32_bf16(kf1, qf[0][1], S0[jt], 0, 0, 0);
            S1[jt] = __builtin_amdgcn_mfma_f32_16x16x32_bf16(kf1, qf[1][1], S1[jt], 0, 0, 0);
        }
        __builtin_amdgcn_s_setprio(0);
    };

    auto pv2 = [&](short8 (*V)[2], short8* pf0, short8* pf1) {
        __builtin_amdgcn_s_setprio(1);
#pragma unroll
        for (int dt = 0; dt < 4; ++dt) {
#pragma unroll
            for (int ks = 0; ks < 2; ++ks) {
                O0[dt] = __builtin_amdgcn_mfma_f32_16x16x32_bf16(V[dt][ks], pf0[ks], O0[dt], 0, 0, 0);
                O1[dt] = __builtin_amdgcn_mfma_f32_16x16x32_bf16(V[dt][ks], pf1[ks], O1[dt], 0, 0, 0);
            }
        }
        lacc0 = __builtin_amdgcn_mfma_f32_16x16x32_bf16(onesf, pf0[0], lacc0, 0, 0, 0);
        lacc0 = __builtin_amdgcn_mfma_f32_16x16x32_bf16(onesf, pf0[1], lacc0, 0, 0, 0);
        lacc1 = __builtin_amdgcn_mfma_f32_16x16x32_bf16(onesf, pf1[0], lacc1, 0, 0, 0);
        lacc1 = __builtin_amdgcn_mfma_f32_16x16x32_bf16(onesf, pf1[1], lacc1, 0, 0, 0);
        __builtin_amdgcn_s_setprio(0);
    };

    auto softmax_pf = [&](f32x4* S, short8* pf) {
#pragma unroll
        for (int jt = 0; jt < 4; ++jt)
#pragma unroll
            for (int r = 0; r < 4; ++r)
                S[jt][r] = __builtin_amdgcn_exp2f(S[jt][r]);
#pragma unroll
        for (int ks = 0; ks < 2; ++ks) {
            u32x4 p;
            p[0] = cvt_pk_bf16(S[2 * ks][0],     S[2 * ks][1]);
            p[1] = cvt_pk_bf16(S[2 * ks][2],     S[2 * ks][3]);
            p[2] = cvt_pk_bf16(S[2 * ks + 1][0], S[2 * ks + 1][1]);
            p[3] = cvt_pk_bf16(S[2 * ks + 1][2], S[2 * ks + 1][3]);
            pf[ks] = __builtin_bit_cast(short8, p);
        }
    };

    f32x4 Sa0[4], Sa1[4], Sb0[4], Sb1[4];
    short8 vfA[4][2], vfB[4][2];

    // body(tt): qk2 tile tt+1; loadV tile tt+1 -> VB; stage K tile tt+3;
    // softmax+PV tile tt (V from VA regs). Barrier allows {VB 8, K(tt+3) 2}.
    auto body = [&](int KR, int KW, f32x4* SC0, f32x4* SC1,
                    f32x4* SN0, f32x4* SN1,
                    short8 (*VA)[2], short8 (*VB)[2], int tt, int drain) {
        qk2(KR, SN0, SN1);
        loadV(VB, (tt + 1) * 64);
        if (tt + 3 < NT_) stageK(KW, (tt + 3) * 64);
        short8 pf0[2], pf1[2];
        softmax_pf(SC0, pf0);
        softmax_pf(SC1, pf1);
        pv2(VA, pf0, pf1);
        if (drain == 10)     asm volatile("s_waitcnt vmcnt(10)" ::: "memory");
        else                 asm volatile("s_waitcnt vmcnt(8)" ::: "memory");
        __builtin_amdgcn_s_barrier();
    };

    // prologue: K(0..2); drain; QK(0); V(0) -> vfA
    stageK(0, 0); stageK(1, 64); stageK(2, 128);
    asm volatile("s_waitcnt vmcnt(0)" ::: "memory");
    __builtin_amdgcn_s_barrier();
    qk2(0, Sa0, Sa1);
    loadV(vfA, 0);

    for (int g = 0; g < 15; ++g) {
        body(1, 3, Sa0, Sa1, Sb0, Sb1, vfA, vfB, 4 * g + 0, 10);
        body(2, 0, Sb0, Sb1, Sa0, Sa1, vfB, vfA, 4 * g + 1, 10);
        body(3, 1, Sa0, Sa1, Sb0, Sb1, vfA, vfB, 4 * g + 2, 10);
        body(0, 2, Sb0, Sb1, Sa0, Sa1, vfB, vfA, 4 * g + 3, 10);
    }
    body(1, 3, Sa0, Sa1, Sb0, Sb1, vfA, vfB, 60, 10);
    body(2, 0, Sb0, Sb1, Sa0, Sa1, vfB, vfA, 61, 8);
    body(3, 1, Sa0, Sa1, Sb0, Sb1, vfA, vfB, 62, 8);
    {   // tail: tile 63 (S in Sb, V in vfB)
        short8 pf0[2], pf1[2];
        softmax_pf(Sb0, pf0);
        softmax_pf(Sb1, pf1);
        pv2(vfB, pf0, pf1);
    }

    float inv0 = 1.f / lacc0[0], inv1 = 1.f / lacc1[0];
    ushort* ab0 = attT + ((size_t)b * HW_ + i0 + 32 * w + l16) * C_ + h * DH_;
    ushort* ab1 = ab0 + 16 * C_;
#pragma unroll
    for (int dt = 0; dt < 4; ++dt) {
        uint2 p0, p1;
        p0.x = cvt_pk_bf16(O0[dt][0] * inv0, O0[dt][1] * inv0);
        p0.y = cvt_pk_bf16(O0[dt][2] * inv0, O0[dt][3] * inv0);
        *(uint2*)(ab0 + 16 * dt + 4 * lg) = p0;
        p1.x = cvt_pk_bf16(O1[dt][0] * inv1, O1[dt][1] * inv1);
        p1.y = cvt_pk_bf16(O1[dt][2] * inv1, O1[dt][3] * inv1);
        *(uint2*)(ab1 + 16 * dt + 4 * lg) = p1;
    }
}

// ---------------- proj GEMM (bf16 MFMA) + bias + residual ------------------
__global__ __launch_bounds__(256) void proj_gemm(const ushort* __restrict__ wpb,
                                                 const ushort* __restrict__ attT,
                                                 const float* __restrict__ bias,
                                                 const float* __restrict__ x,
                                                 float* __restrict__ out) {
    int n0 = blockIdx.x * 64;
    int o0 = blockIdx.y * 128;
    int b  = blockIdx.z;
    int t = threadIdx.x;
    int w = t >> 6, lane = t & 63, l16 = lane & 15, lg = lane >> 4;
    const ushort* xb = attT + ((size_t)b * HW_ + n0) * C_;
    const ushort* wrow0 = wpb + (size_t)(o0 + 32 * w + l16) * C_;
    const ushort* wrow1 = wrow0 + 16 * C_;

    f32x4 acc[2][4];
#pragma unroll
    for (int os = 0; os < 2; ++os)
#pragma unroll
        for (int u = 0; u < 4; ++u)
#pragma unroll
            for (int r = 0; r < 4; ++r) acc[os][u][r] = 0.f;

#pragma unroll 2
    for (int ks = 0; ks < 8; ++ks) {
        short8 a0 = *(const short8*)(wrow0 + 32 * ks + 8 * lg);
        short8 a1 = *(const short8*)(wrow1 + 32 * ks + 8 * lg);
#pragma unroll
        for (int u = 0; u < 4; ++u) {
            short8 bf = *(const short8*)(xb + (size_t)(16 * u + l16) * C_ + 32 * ks + 8 * lg);
            acc[0][u] = __builtin_amdgcn_mfma_f32_16x16x32_bf16(a0, bf, acc[0][u], 0, 0, 0);
            acc[1][u] = __builtin_amdgcn_mfma_f32_16x16x32_bf16(a1, bf, acc[1][u], 0, 0, 0);
        }
    }

#pragma unroll
    for (int os = 0; os < 2; ++os) {
        int o_base = o0 + 32 * w + 16 * os;
#pragma unroll
        for (int u = 0; u < 4; ++u) {
            int n = n0 + 16 * u + l16;
#pragma unroll
            for (int r = 0; r < 4; ++r) {
                int mrow = o_base + 4 * lg + r;
                size_t idx = ((size_t)(b * C_ + mrow)) * HW_ + n;
                out[idx] = acc[os][u][r] + bias[mrow] + x[idx];
            }
        }
    }
}

extern "C" void kernel_launch(void* const* d_in, const int* in_sizes, int n_in,
                              void* d_out, int out_size, void* d_ws, size_t ws_size,
                              hipStream_t stream) {
    const float* x        = (const float*)d_in[0];
    const float* gn_gamma = (const float*)d_in[1];
    const float* gn_beta  = (const float*)d_in[2];
    const float* w_qkv    = (const float*)d_in[3];
    const float* w_proj   = (const float*)d_in[4];
    const float* b_proj   = (const float*)d_in[5];
    float* out = (float*)d_out;

    ushort* wsp  = (ushort*)d_ws;
    ushort* qt   = wsp;                       // 16*4096*64
    ushort* kt   = qt   + 4194304;
    ushort* vv   = kt   + 4194304;            // 4*256*4096
    ushort* attT = vv   + 4194304;            // 4*4096*256
    ushort* wqb  = attT + 4194304;            // 768*256
    ushort* wpb  = wqb  + 196608;             // 256*256
    float*  part = (float*)(wpb + 65536);     // 512 floats

    gn_part_wcvt<<<dim3(512 + 1024), 256, 0, stream>>>(x, part, w_qkv, w_proj, wqb, wpb);
    gn_qkv<<<dim3(HW_ / 64, B_), 256, 0, stream>>>(x, gn_gamma, gn_beta, part, wqb, qt, kt, vv);
    flash_attn_mfma<<<dim3(512), 256, 0, stream>>>(qt, kt, vv, attT);
    proj_gemm<<<dim3(HW_ / 64, 2, B_), 256, 0, stream>>>(wpb, attT, b_proj, x, out);
}

// Round 15
// 115.219 us; speedup vs baseline: 1.8371x; 1.8371x over previous
//
#include <hip/hip_runtime.h>
#include <math.h>
#include <stdint.h>

#define B_ 4
#define C_ 256
#define HW_ 4096
#define G_ 8
#define H_ 4
#define DH_ 64
#define GRP_ELEMS (32 * HW_)             // 131072
#define NCHUNK 16
#define CHUNK_ELEMS (GRP_ELEMS / NCHUNK) // 8192
#define EPS 1e-5f
#define NT_ (HW_ / 64)                   // 64 j-tiles
#define QSCALE 0.04508422f               // (1/32) * log2(e)

typedef __attribute__((ext_vector_type(8))) short short8;
typedef __attribute__((ext_vector_type(4))) float f32x4;
typedef __attribute__((ext_vector_type(4))) unsigned int u32x4;
typedef const __attribute__((address_space(1))) uint32_t* gas1_t;
typedef __attribute__((address_space(3))) uint32_t* las3_t;

__device__ __forceinline__ ushort f2bf(float x) {
    unsigned u = __builtin_bit_cast(unsigned, x);
    u += 0x7FFFu + ((u >> 16) & 1u);
    return (ushort)(u >> 16);
}
__device__ __forceinline__ uint32_t cvt_pk_bf16(float lo, float hi) {
    uint32_t r;
    asm("v_cvt_pk_bf16_f32 %0, %1, %2" : "=v"(r) : "v"(lo), "v"(hi));
    return r;
}

// ---------------- GN stage-1 partial sums + weight convert (merged) --------
__global__ __launch_bounds__(256) void gn_part_wcvt(const float* __restrict__ x,
                                                    float* __restrict__ part,
                                                    const float* __restrict__ wq,
                                                    const float* __restrict__ wp,
                                                    ushort* __restrict__ wqb,
                                                    ushort* __restrict__ wpb) {
    int t = threadIdx.x;
    if (blockIdx.x >= 512) {          // weight convert: 1024 blocks
        int i = (blockIdx.x - 512) * 256 + t;
        if (i < 768 * 256) {
            float s = (i < 256 * 256) ? QSCALE : 1.0f;
            wqb[i] = f2bf(wq[i] * s);
        } else {
            wpb[i - 768 * 256] = f2bf(wp[i - 768 * 256]);
        }
        return;
    }
    int bg = blockIdx.x >> 4;
    int chunk = blockIdx.x & 15;
    const float4* p = (const float4*)(x + (size_t)bg * GRP_ELEMS + (size_t)chunk * CHUNK_ELEMS);
    float s = 0.f, ss = 0.f;
#pragma unroll
    for (int i = 0; i < 8; ++i) {
        float4 v = p[t + i * 256];
        s  += v.x + v.y + v.z + v.w;
        ss += v.x * v.x + v.y * v.y + v.z * v.z + v.w * v.w;
    }
#pragma unroll
    for (int off = 32; off; off >>= 1) {
        s  += __shfl_xor(s, off, 64);
        ss += __shfl_xor(ss, off, 64);
    }
    __shared__ float ls[8];
    int wave = t >> 6, lane = t & 63;
    if (lane == 0) { ls[wave * 2] = s; ls[wave * 2 + 1] = ss; }
    __syncthreads();
    if (t == 0) {
        float S = 0.f, SS = 0.f;
#pragma unroll
        for (int w = 0; w < 4; ++w) { S += ls[w * 2]; SS += ls[w * 2 + 1]; }
        part[(bg * 16 + chunk) * 2]     = S;
        part[(bg * 16 + chunk) * 2 + 1] = SS;
    }
}

// ---------------- fused GroupNorm + QKV GEMM (round-13, unchanged) ---------
#define TSTR 264
__global__ __launch_bounds__(256) void gn_qkv(const float* __restrict__ x,
                                              const float* __restrict__ gamma,
                                              const float* __restrict__ beta,
                                              const float* __restrict__ part,
                                              const ushort* __restrict__ wqb,
                                              ushort* __restrict__ qt,
                                              ushort* __restrict__ kt,
                                              ushort* __restrict__ vv) {
    __shared__ float2 affs[256];
    __shared__ __align__(16) ushort Ts[64 * TSTR];
    int n0 = blockIdx.x * 64;
    int b  = blockIdx.y;
    int t = threadIdx.x;

    {
        int c = t;
        int bg = b * G_ + (c >> 5);
        float S = 0.f, SS = 0.f;
#pragma unroll
        for (int i = 0; i < 16; ++i) {
            S  += part[(bg * 16 + i) * 2];
            SS += part[(bg * 16 + i) * 2 + 1];
        }
        float mean = S * (1.f / GRP_ELEMS);
        float var  = SS * (1.f / GRP_ELEMS) - mean * mean;
        float inv  = rsqrtf(var + EPS);
        float a = inv * gamma[c];
        affs[c] = make_float2(a, beta[c] - mean * a);
    }
    __syncthreads();

    {
        int n4 = t & 15, cr = t >> 4;
#pragma unroll
        for (int ct = 0; ct < 16; ++ct) {
            int c = cr + 16 * ct;
            float2 p = affs[c];
            float4 v = *(const float4*)(x + ((size_t)(b * C_ + c)) * HW_ + n0 + n4 * 4);
            ushort e[4];
            e[0] = f2bf(v.x * p.x + p.y); e[1] = f2bf(v.y * p.x + p.y);
            e[2] = f2bf(v.z * p.x + p.y); e[3] = f2bf(v.w * p.x + p.y);
#pragma unroll
            for (int k = 0; k < 4; ++k) {
                int n = n4 * 4 + k;
                Ts[n * TSTR + (((c >> 3) ^ ((n >> 2) & 7)) << 3) + (c & 7)] = e[k];
            }
        }
    }
    __syncthreads();

    int w = t >> 6, lane = t & 63, l16 = lane & 15, lg = lane >> 4;

    for (int z = 0; z < 3; ++z) {
        const ushort* wz = wqb + (size_t)(z * 256 + 32 * w + l16) * C_;
        f32x4 acc[2][2][4];
#pragma unroll
        for (int j = 0; j < 2; ++j)
#pragma unroll
            for (int os = 0; os < 2; ++os)
#pragma unroll
                for (int u = 0; u < 4; ++u)
#pragma unroll
                    for (int r = 0; r < 4; ++r) acc[j][os][u][r] = 0.f;

#pragma unroll 2
        for (int ks = 0; ks < 8; ++ks) {
            short8 a00 = *(const short8*)(wz + 32 * ks + 8 * lg);
            short8 a01 = *(const short8*)(wz + 16 * C_ + 32 * ks + 8 * lg);
            short8 a10 = *(const short8*)(wz + 128 * C_ + 32 * ks + 8 * lg);
            short8 a11 = *(const short8*)(wz + 144 * C_ + 32 * ks + 8 * lg);
#pragma unroll
            for (int u = 0; u < 4; ++u) {
                int n = 16 * u + l16;
                short8 bf = *(const short8*)&Ts[n * TSTR +
                               (((4 * ks + lg) ^ ((n >> 2) & 7)) << 3)];
                acc[0][0][u] = __builtin_amdgcn_mfma_f32_16x16x32_bf16(a00, bf, acc[0][0][u], 0, 0, 0);
                acc[0][1][u] = __builtin_amdgcn_mfma_f32_16x16x32_bf16(a01, bf, acc[0][1][u], 0, 0, 0);
                acc[1][0][u] = __builtin_amdgcn_mfma_f32_16x16x32_bf16(a10, bf, acc[1][0][u], 0, 0, 0);
                acc[1][1][u] = __builtin_amdgcn_mfma_f32_16x16x32_bf16(a11, bf, acc[1][1][u], 0, 0, 0);
            }
        }

#pragma unroll
        for (int j = 0; j < 2; ++j)
#pragma unroll
            for (int os = 0; os < 2; ++os) {
                int o_base = z * 256 + 128 * j + 32 * w + 16 * os;
                if (z < 2) {
                    int h = (o_base >> 6) & 3;
                    int od0 = (o_base & 63) + 4 * lg;
                    ushort* dstb = (z ? kt : qt) + ((size_t)((b << 2) | h) * HW_) * DH_;
#pragma unroll
                    for (int u = 0; u < 4; ++u) {
                        int n = n0 + 16 * u + l16;
                        uint2 pk;
                        pk.x = cvt_pk_bf16(acc[j][os][u][0], acc[j][os][u][1]);
                        pk.y = cvt_pk_bf16(acc[j][os][u][2], acc[j][os][u][3]);
                        *(uint2*)(dstb + (size_t)n * DH_ + od0) = pk;
                    }
                } else {
                    int row0 = o_base - 512 + 4 * lg;
#pragma unroll
                    for (int u = 0; u < 4; ++u) {
                        int n = n0 + 16 * u + l16;
#pragma unroll
                        for (int r = 0; r < 4; ++r)
                            vv[((size_t)(b * C_ + row0 + r)) * HW_ + n] = f2bf(acc[j][os][u][r]);
                    }
                }
            }
    }
}

// ---------------- MFMA flash attention v9.1 (round-13 exact, validated) ----
__global__ __launch_bounds__(256) void flash_attn_mfma(const ushort* __restrict__ qt,
                                                       const ushort* __restrict__ kt,
                                                       const ushort* __restrict__ vv,
                                                       ushort* __restrict__ attT) {
    __shared__ __align__(16) ushort Kb[4][64 * 64];   // [perm row][dh], chunks swz
    __shared__ __align__(16) ushort Vb[4][64 * 64];   // [d][j],  chunks swz

    int bid = blockIdx.x;
    int wg = (bid & 7) * 64 + (bid >> 3);   // bijective: 512 = 8 * 64
    int bh = wg >> 5;
    int i0 = (wg & 31) * 128;
    int b = bh >> 2, h = bh & 3;
    int t = threadIdx.x;
    int w = t >> 6, lane = t & 63, l16 = lane & 15, lg = lane >> 4;
    const ushort* qtb = qt + (size_t)bh * HW_ * DH_;
    const ushort* ktb = kt + (size_t)bh * HW_ * DH_;
    const ushort* vb  = vv + ((size_t)(b * C_) + h * DH_) * HW_;

    short8 qf[2][2];
#pragma unroll
    for (int s = 0; s < 2; ++s)
#pragma unroll
        for (int ks = 0; ks < 2; ++ks)
            qf[s][ks] = *(const short8*)(qtb + (size_t)(i0 + 32 * w + 16 * s + l16) * DH_ + 32 * ks + 8 * lg);

    f32x4 O0[4], O1[4], lacc0, lacc1;
#pragma unroll
    for (int dt = 0; dt < 4; ++dt)
#pragma unroll
        for (int r = 0; r < 4; ++r) { O0[dt][r] = 0.f; O1[dt][r] = 0.f; }
#pragma unroll
    for (int r = 0; r < 4; ++r) { lacc0[r] = 0.f; lacc1[r] = 0.f; }
    const f32x4 Z4 = {0.f, 0.f, 0.f, 0.f};

    u32x4 ov; ov[0] = ov[1] = ov[2] = ov[3] = 0x3F803F80u;
    short8 onesf = __builtin_bit_cast(short8, ov);

    int r8 = lane >> 3, ch8 = lane & 7;
    size_t koff[2], voff[2];
#pragma unroll
    for (int half = 0; half < 2; ++half) {
        int L = 16 * w + half * 8 + r8;
        int gk = (L & 0x23) | ((L & 0x0C) << 1) | ((L & 0x10) >> 2);
        koff[half] = (size_t)gk * DH_ + ((ch8 ^ (L & 7)) << 3);
        voff[half] = (size_t)L * HW_ + ((ch8 ^ (L & 7)) << 3);
    }

    auto stageK = [&](int bi, int j0) {
#pragma unroll
        for (int half = 0; half < 2; ++half) {
            int rowb = 16 * w + half * 8;
            __builtin_amdgcn_global_load_lds((gas1_t)(ktb + (size_t)j0 * DH_ + koff[half]),
                (las3_t)&Kb[bi][rowb * 64], 16, 0, 0);
        }
    };
    auto stageV = [&](int bi, int j0) {
#pragma unroll
        for (int half = 0; half < 2; ++half) {
            int rowb = 16 * w + half * 8;
            __builtin_amdgcn_global_load_lds((gas1_t)(vb + (size_t)j0 + voff[half]),
                (las3_t)&Vb[bi][rowb * 64], 16, 0, 0);
        }
    };

    auto qk2 = [&](int bi, f32x4* S0, f32x4* S1) {
        __builtin_amdgcn_s_setprio(1);
#pragma unroll
        for (int jt = 0; jt < 4; ++jt) {
            short8 kf0 = *(const short8*)&Kb[bi][(16 * jt + l16) * 64 +
                                                ((lg ^ (l16 & 7)) << 3)];
            S0[jt] = __builtin_amdgcn_mfma_f32_16x16x32_bf16(kf0, qf[0][0], Z4, 0, 0, 0);
            S1[jt] = __builtin_amdgcn_mfma_f32_16x16x32_bf16(kf0, qf[1][0], Z4, 0, 0, 0);
            short8 kf1 = *(const short8*)&Kb[bi][(16 * jt + l16) * 64 +
                                                (((4 + lg) ^ (l16 & 7)) << 3)];
            S0[jt] = __builtin_amdgcn_mfma_f32_16x16x32_bf16(kf1, qf[0][1], S0[jt], 0, 0, 0);
            S1[jt] = __builtin_amdgcn_mfma_f32_16x16x32_bf16(kf1, qf[1][1], S1[jt], 0, 0, 0);
        }
        __builtin_amdgcn_s_setprio(0);
    };

    auto pv2 = [&](int bi, short8* pf0, short8* pf1) {
        __builtin_amdgcn_s_setprio(1);
#pragma unroll
        for (int dt = 0; dt < 4; ++dt) {
#pragma unroll
            for (int ks = 0; ks < 2; ++ks) {
                short8 vf = *(const short8*)&Vb[bi][(16 * dt + l16) * 64 +
                                                    (((4 * ks + lg) ^ (l16 & 7)) << 3)];
                O0[dt] = __builtin_amdgcn_mfma_f32_16x16x32_bf16(vf, pf0[ks], O0[dt], 0, 0, 0);
                O1[dt] = __builtin_amdgcn_mfma_f32_16x16x32_bf16(vf, pf1[ks], O1[dt], 0, 0, 0);
            }
        }
        lacc0 = __builtin_amdgcn_mfma_f32_16x16x32_bf16(onesf, pf0[0], lacc0, 0, 0, 0);
        lacc0 = __builtin_amdgcn_mfma_f32_16x16x32_bf16(onesf, pf0[1], lacc0, 0, 0, 0);
        lacc1 = __builtin_amdgcn_mfma_f32_16x16x32_bf16(onesf, pf1[0], lacc1, 0, 0, 0);
        lacc1 = __builtin_amdgcn_mfma_f32_16x16x32_bf16(onesf, pf1[1], lacc1, 0, 0, 0);
        __builtin_amdgcn_s_setprio(0);
    };

    auto softmax_pf = [&](f32x4* S, short8* pf) {
#pragma unroll
        for (int jt = 0; jt < 4; ++jt)
#pragma unroll
            for (int r = 0; r < 4; ++r)
                S[jt][r] = __builtin_amdgcn_exp2f(S[jt][r]);
#pragma unroll
        for (int ks = 0; ks < 2; ++ks) {
            u32x4 p;
            p[0] = cvt_pk_bf16(S[2 * ks][0],     S[2 * ks][1]);
            p[1] = cvt_pk_bf16(S[2 * ks][2],     S[2 * ks][3]);
            p[2] = cvt_pk_bf16(S[2 * ks + 1][0], S[2 * ks + 1][1]);
            p[3] = cvt_pk_bf16(S[2 * ks + 1][2], S[2 * ks + 1][3]);
            pf[ks] = __builtin_bit_cast(short8, p);
        }
    };

    f32x4 Sa0[4], Sa1[4], Sb0[4], Sb1[4];

    auto body = [&](int VW, int KR, int KW, int VR,
                    f32x4* SC0, f32x4* SC1, f32x4* SN0, f32x4* SN1,
                    int tt, int drain) {
        if (tt + 2 < NT_) stageV(VW, (tt + 2) * 64);
        qk2(KR, SN0, SN1);
        if (tt + 3 < NT_) stageK(KW, (tt + 3) * 64);
        short8 pf0[2], pf1[2];
        softmax_pf(SC0, pf0);
        softmax_pf(SC1, pf1);
        pv2(VR, pf0, pf1);
        if (drain == 8)      asm volatile("s_waitcnt vmcnt(8)" ::: "memory");
        else if (drain == 4) asm volatile("s_waitcnt vmcnt(4)" ::: "memory");
        else                 asm volatile("s_waitcnt vmcnt(0)" ::: "memory");
        __builtin_amdgcn_s_barrier();
    };

    stageK(0, 0); stageV(0, 0);
    stageK(1, 64); stageV(1, 64);
    stageK(2, 128);
    asm volatile("s_waitcnt vmcnt(0)" ::: "memory");
    __builtin_amdgcn_s_barrier();
    qk2(0, Sa0, Sa1);

    for (int g = 0; g < 15; ++g) {
        body(2, 1, 3, 0, Sa0, Sa1, Sb0, Sb1, 4 * g + 0, 8);
        body(3, 2, 0, 1, Sb0, Sb1, Sa0, Sa1, 4 * g + 1, 8);
        body(0, 3, 1, 2, Sa0, Sa1, Sb0, Sb1, 4 * g + 2, 8);
        body(1, 0, 2, 3, Sb0, Sb1, Sa0, Sa1, 4 * g + 3, 8);
    }
    body(2, 1, 3, 0, Sa0, Sa1, Sb0, Sb1, 60, 8);
    body(3, 2, 0, 1, Sb0, Sb1, Sa0, Sa1, 61, 4);
    body(0, 3, 1, 2, Sa0, Sa1, Sb0, Sb1, 62, 0);
    {
        short8 pf0[2], pf1[2];
        softmax_pf(Sb0, pf0);
        softmax_pf(Sb1, pf1);
        pv2(3, pf0, pf1);
    }

    float inv0 = 1.f / lacc0[0], inv1 = 1.f / lacc1[0];
    ushort* ab0 = attT + ((size_t)b * HW_ + i0 + 32 * w + l16) * C_ + h * DH_;
    ushort* ab1 = ab0 + 16 * C_;
#pragma unroll
    for (int dt = 0; dt < 4; ++dt) {
        uint2 p0, p1;
        p0.x = cvt_pk_bf16(O0[dt][0] * inv0, O0[dt][1] * inv0);
        p0.y = cvt_pk_bf16(O0[dt][2] * inv0, O0[dt][3] * inv0);
        *(uint2*)(ab0 + 16 * dt + 4 * lg) = p0;
        p1.x = cvt_pk_bf16(O1[dt][0] * inv1, O1[dt][1] * inv1);
        p1.y = cvt_pk_bf16(O1[dt][2] * inv1, O1[dt][3] * inv1);
        *(uint2*)(ab1 + 16 * dt + 4 * lg) = p1;
    }
}

// ---------------- proj GEMM + bias + residual, LDS-staged attT tile --------
// grid (HW/64, 2, B). attT n-tile [64][256] staged once into swizzled LDS
// (shared by all 4 waves) instead of 4x per-wave global re-reads.
__global__ __launch_bounds__(256) void proj_gemm(const ushort* __restrict__ wpb,
                                                 const ushort* __restrict__ attT,
                                                 const float* __restrict__ bias,
                                                 const float* __restrict__ x,
                                                 float* __restrict__ out) {
    __shared__ __align__(16) ushort Ts[64 * TSTR];
    int n0 = blockIdx.x * 64;
    int o0 = blockIdx.y * 128;
    int b  = blockIdx.z;
    int t = threadIdx.x;
    int w = t >> 6, lane = t & 63, l16 = lane & 15, lg = lane >> 4;
    const ushort* xb = attT + ((size_t)b * HW_ + n0) * C_;

    {   // stage attT tile -> Ts (swizzled chunks), coalesced uint4 loads
#pragma unroll
        for (int i = 0; i < 8; ++i) {
            int q = t + 256 * i;          // chunk id: row n = q>>5, c8 = q&31
            int n = q >> 5, c8 = q & 31;
            uint4 v = *(const uint4*)(xb + (size_t)n * C_ + c8 * 8);
            *(uint4*)&Ts[n * TSTR + ((c8 ^ ((n >> 2) & 7)) << 3)] = v;
        }
    }
    __syncthreads();

    const ushort* wrow0 = wpb + (size_t)(o0 + 32 * w + l16) * C_;
    const ushort* wrow1 = wrow0 + 16 * C_;

    f32x4 acc[2][4];
#pragma unroll
    for (int os = 0; os < 2; ++os)
#pragma unroll
        for (int u = 0; u < 4; ++u)
#pragma unroll
            for (int r = 0; r < 4; ++r) acc[os][u][r] = 0.f;

#pragma unroll 2
    for (int ks = 0; ks < 8; ++ks) {
        short8 a0 = *(const short8*)(wrow0 + 32 * ks + 8 * lg);
        short8 a1 = *(const short8*)(wrow1 + 32 * ks + 8 * lg);
#pragma unroll
        for (int u = 0; u < 4; ++u) {
            int n = 16 * u + l16;
            short8 bf = *(const short8*)&Ts[n * TSTR +
                           (((4 * ks + lg) ^ ((n >> 2) & 7)) << 3)];
            acc[0][u] = __builtin_amdgcn_mfma_f32_16x16x32_bf16(a0, bf, acc[0][u], 0, 0, 0);
            acc[1][u] = __builtin_amdgcn_mfma_f32_16x16x32_bf16(a1, bf, acc[1][u], 0, 0, 0);
        }
    }

#pragma unroll
    for (int os = 0; os < 2; ++os) {
        int o_base = o0 + 32 * w + 16 * os;
#pragma unroll
        for (int u = 0; u < 4; ++u) {
            int n = n0 + 16 * u + l16;
#pragma unroll
            for (int r = 0; r < 4; ++r) {
                int mrow = o_base + 4 * lg + r;
                size_t idx = ((size_t)(b * C_ + mrow)) * HW_ + n;
                out[idx] = acc[os][u][r] + bias[mrow] + x[idx];
            }
        }
    }
}

extern "C" void kernel_launch(void* const* d_in, const int* in_sizes, int n_in,
                              void* d_out, int out_size, void* d_ws, size_t ws_size,
                              hipStream_t stream) {
    const float* x        = (const float*)d_in[0];
    const float* gn_gamma = (const float*)d_in[1];
    const float* gn_beta  = (const float*)d_in[2];
    const float* w_qkv    = (const float*)d_in[3];
    const float* w_proj   = (const float*)d_in[4];
    const float* b_proj   = (const float*)d_in[5];
    float* out = (float*)d_out;

    ushort* wsp  = (ushort*)d_ws;
    ushort* qt   = wsp;                       // 16*4096*64
    ushort* kt   = qt   + 4194304;
    ushort* vv   = kt   + 4194304;            // 4*256*4096
    ushort* attT = vv   + 4194304;            // 4*4096*256
    ushort* wqb  = attT + 4194304;            // 768*256
    ushort* wpb  = wqb  + 196608;             // 256*256
    float*  part = (float*)(wpb + 65536);     // 512 floats

    gn_part_wcvt<<<dim3(512 + 1024), 256, 0, stream>>>(x, part, w_qkv, w_proj, wqb, wpb);
    gn_qkv<<<dim3(HW_ / 64, B_), 256, 0, stream>>>(x, gn_gamma, gn_beta, part, wqb, qt, kt, vv);
    flash_attn_mfma<<<dim3(512), 256, 0, stream>>>(qt, kt, vv, attT);
    proj_gemm<<<dim3(HW_ / 64, 2, B_), 256, 0, stream>>>(wpb, attT, b_proj, x, out);
}